// Round 8
// baseline (327.348 us; speedup 1.0000x reference)
//
#include <hip/hip_runtime.h>
#include <hip/hip_bf16.h>
#include <cstdint>
#include <cstddef>

typedef __bf16 bf16;
typedef bf16 bf16x8 __attribute__((ext_vector_type(8)));
typedef bf16 bf16x4 __attribute__((ext_vector_type(4)));
typedef float f32x4 __attribute__((ext_vector_type(4)));
typedef unsigned int u32;

#define DEV static __device__ __forceinline__

DEV f32x4 mfma16(bf16x8 a, bf16x8 b, f32x4 c) {
    return __builtin_amdgcn_mfma_f32_16x16x32_bf16(a, b, c, 0, 0, 0);
}

DEV f32x4 shflx4(f32x4 v, int m) {
    f32x4 r;
    for (int i = 0; i < 4; ++i) r[i] = __shfl_xor(v[i], m, 64);
    return r;
}

DEV bf16x8 cvt8(const float* p) {
    float4 f0 = *(const float4*)p;
    float4 f1 = *(const float4*)(p + 4);
    bf16x8 v;
    v[0] = (bf16)f0.x; v[1] = (bf16)f0.y; v[2] = (bf16)f0.z; v[3] = (bf16)f0.w;
    v[4] = (bf16)f1.x; v[5] = (bf16)f1.y; v[6] = (bf16)f1.z; v[7] = (bf16)f1.w;
    return v;
}

// async global->LDS, 16B/lane; global addr per-lane, LDS base wave-uniform.
DEV void glo(const bf16* g, bf16* l) {
    __builtin_amdgcn_global_load_lds(
        (const __attribute__((address_space(1))) u32*)g,
        (__attribute__((address_space(3))) u32*)l,
        16, 0, 0);
}

// fused "wait outstanding vmem <= n, then barrier" — counted, never reorder.
#define WAITB(n) asm volatile("s_waitcnt vmcnt(" #n ")\n\ts_barrier" ::: "memory")
#define BAR()    asm volatile("s_barrier" ::: "memory")

// ---------------------------------------------------------------------------
// Prep (merged): z<6 : weight transpose+cvt W[K][N]fp32 -> Wt[N][K]bf16
//                z 6..10 : fp32->bf16 cvt of the 5 activations
//                z 11..14 : maskprep for b = z-11 (blockIdx.y<8 active)
// grid (16, 16, 15), 256 threads. (Reverted to r5: fusing act-cvt into proj
// spilled registers twice — r6 VGPR=64, r7 VGPR=80 — both regressed.)
// ---------------------------------------------------------------------------
struct PrepArgs {
    const float* w[6];
    const float* act[5];
    const float* mask;
    bf16* wdst[6];  int wstride[6];
    bf16* adst[5];  int astride[5];
    bf16* maskR;
};

__global__ __launch_bounds__(256) void prep_kernel(PrepArgs p)
{
    const int z = blockIdx.z;
    const int t = threadIdx.x;
    if (z < 6) {
        __shared__ bf16 tile[64][72];
        const float* src = p.w[z];
        bf16* out = p.wdst[z];
        const int os = p.wstride[z];
        const int r = t >> 3, c8 = (t & 7) * 8;
        const int row0 = blockIdx.y * 64, col0 = blockIdx.x * 64;
        *(bf16x8*)&tile[r][c8]      = cvt8(&src[(size_t)(row0 + r) * 1024 + col0 + c8]);
        *(bf16x8*)&tile[r + 32][c8] = cvt8(&src[(size_t)(row0 + r + 32) * 1024 + col0 + c8]);
        __syncthreads();
        for (int half = 0; half < 2; ++half) {
            int rr = r + half * 32;
            bf16x8 v;
            for (int j = 0; j < 8; ++j) v[j] = tile[c8 + j][rr];
            *(bf16x8*)&out[(size_t)(col0 + rr) * os + row0 + c8] = v;
        }
    } else if (z < 11) {
        const float* src = p.act[z - 6];
        bf16* dst = p.adst[z - 6];
        const int as = p.astride[z - 6];
        const size_t chunk = (size_t)(blockIdx.y * 16 + blockIdx.x) * 16384;
        for (int c = 0; c < 8; ++c) {
            const size_t off = chunk + (size_t)c * 2048 + (size_t)t * 8;
            const size_t row = off >> 10, col = off & 1023;
            *(bf16x8*)&dst[row * (size_t)as + col] = cvt8(&src[off]);
        }
    } else {
        // maskprep: mask[b][i][j] fp32 -> maskR[(b,it,jt)][tid][e] bf16
        if (blockIdx.y >= 8) return;
        const int jt = blockIdx.x, it = blockIdx.y, b = z - 11;
        __shared__ bf16 Mt[128 * 72];
        const int lane = t & 63, w = t >> 6;
        const int ln = lane & 15, qd = lane >> 4;
        {
            const int il = t >> 1, jh = (t & 1) * 32;
            const float* src = &p.mask[((size_t)b * 1024 + it * 128 + il) * 1024 + jt * 64 + jh];
            *(bf16x8*)&Mt[il * 72 + jh]      = cvt8(src);
            *(bf16x8*)&Mt[il * 72 + jh + 8]  = cvt8(src + 8);
            *(bf16x8*)&Mt[il * 72 + jh + 16] = cvt8(src + 16);
            *(bf16x8*)&Mt[il * 72 + jh + 24] = cvt8(src + 24);
        }
        __syncthreads();
        bf16 m[32];
        for (int si = 0; si < 2; ++si)
            for (int jc = 0; jc < 4; ++jc)
                for (int r = 0; r < 4; ++r) {
                    const int il = w * 32 + si * 16 + qd * 4 + r;
                    const int jl = jc * 16 + ln;
                    m[(si * 4 + jc) * 4 + r] = Mt[il * 72 + jl];
                }
        bf16* dst = &p.maskR[((((size_t)b * 8 + it) * 16 + jt) * 256 + t) * 32];
        for (int c = 0; c < 4; ++c)
            *(bf16x8*)&dst[c * 8] = *(const bf16x8*)&m[c * 8];
    }
}

// ---------------------------------------------------------------------------
// Projection GEMMs, 4 z-slices — 256x256 tile, 4-phase interleaved schedule
// (T3+T4+T5, the catalog's verified 256²+8ph regime; r1/r2's 2-phase attempts
// were the null quadrant). 512 thr = 8 waves (2M x 4N), wave owns 128x64
// (acc[8][4] = 128 VGPR; __launch_bounds__(512,2) -> 256 budget, no spill).
// LDS 128KB: dbuf x (A[256][64] + B[256][64]), 1 block/CU (m201's regime).
// Per K-tile t: 4 phases, each { ds_read quadrant frags | issue 2-3 glo of
// tile t+1 into buf^1 | BAR | setprio(1) 16 MFMA setprio(0) | BAR }; tile
// boundary = vmcnt(0)+BAR where every drained load had 2-4 phases of cover
// (issue-early / drain-late). Proven-0-conflict XOR swizzle kept verbatim.
// z0 = fused Vsum GEMM ([value|time_v] @ [Wv;Wtv], K=2048, vst out [d][s]).
// Grid (16,4,4) = 256 blocks = 1/CU; same-A (same-x) blocks share an XCD.
// ---------------------------------------------------------------------------
struct ProjArgs {
    const bf16* A[4];
    const bf16* W[4];
    const float* bias[4];
    const float* bias2[4];
    bf16* out[4];
    int vst[4];
    int nk[4];
};

__global__ __launch_bounds__(512, 2) void proj_gemm(ProjArgs pa)
{
    const int z = blockIdx.z;
    const bf16* __restrict__ A = pa.A[z];
    const bf16* __restrict__ W = pa.W[z];
    const int nk = pa.nk[z];
    const int lda = nk << 6;
    const int m0 = blockIdx.x * 256, n0 = blockIdx.y * 256;
    __shared__ bf16 As[2][256 * 64];
    __shared__ bf16 Bs[2][256 * 64];
    const int t = threadIdx.x, lane = t & 63, w = t >> 6;
    const int ln = lane & 15, qd = lane >> 4;
    const int wm0 = (w >> 2) * 128, wn0 = (w & 3) * 64;
    const int rr = lane >> 3;
    const int cbs = ((lane & 7) ^ rr) * 8;     // swizzled source column
    const int lx = ln & 7;                     // row&7 for fragment rows
    const int u0 = w * 4;                      // this wave's staging units

    f32x4 acc[8][4];
    for (int i = 0; i < 8; ++i)
        for (int j = 0; j < 4; ++j)
            acc[i][j] = (f32x4){0.f, 0.f, 0.f, 0.f};

    // staging unit u0+i covers 8 rows (u*8+rr), one glo per wave per unit.
#define SA(ks_, i_, b_) glo(&A[(size_t)(m0 + (u0 + (i_)) * 8 + rr) * lda + (ks_) * 64 + cbs], \
                            &As[b_][(u0 + (i_)) * 512])
#define SB(ks_, i_, b_) glo(&W[(size_t)(n0 + (u0 + (i_)) * 8 + rr) * lda + (ks_) * 64 + cbs], \
                            &Bs[b_][(u0 + (i_)) * 512])

    // prologue: stage tile 0 into buf 0, drain, barrier.
    SA(0, 0, 0); SA(0, 1, 0); SA(0, 2, 0); SA(0, 3, 0);
    SB(0, 0, 0); SB(0, 1, 0); SB(0, 2, 0); SB(0, 3, 0);
    WAITB(0);

    for (int ks = 0; ks < nk; ++ks) {
        const int cur = ks & 1, nxt = cur ^ 1;
        const bool pf = (ks + 1 < nk);
        bf16x8 af[4], bfr[4];
        // ---- phase 0: kc=0, m-half 0 -------------------------------------
        {
            const int sg = (qd ^ lx) * 8;
            for (int ni = 0; ni < 4; ++ni)
                bfr[ni] = *(const bf16x8*)&Bs[cur][(wn0 + ni * 16 + ln) * 64 + sg];
            for (int mi = 0; mi < 4; ++mi)
                af[mi] = *(const bf16x8*)&As[cur][(wm0 + mi * 16 + ln) * 64 + sg];
            if (pf) { SA(ks + 1, 0, nxt); SA(ks + 1, 1, nxt); SA(ks + 1, 2, nxt); }
            BAR();
            __builtin_amdgcn_s_setprio(1);
            for (int mi = 0; mi < 4; ++mi)
                for (int ni = 0; ni < 4; ++ni)
                    acc[mi][ni] = mfma16(af[mi], bfr[ni], acc[mi][ni]);
            __builtin_amdgcn_s_setprio(0);
            BAR();
        }
        // ---- phase 1: kc=0, m-half 1 -------------------------------------
        {
            const int sg = (qd ^ lx) * 8;
            for (int mi = 0; mi < 4; ++mi)
                af[mi] = *(const bf16x8*)&As[cur][(wm0 + 64 + mi * 16 + ln) * 64 + sg];
            if (pf) { SA(ks + 1, 3, nxt); SB(ks + 1, 0, nxt); SB(ks + 1, 1, nxt); }
            BAR();
            __builtin_amdgcn_s_setprio(1);
            for (int mi = 0; mi < 4; ++mi)
                for (int ni = 0; ni < 4; ++ni)
                    acc[4 + mi][ni] = mfma16(af[mi], bfr[ni], acc[4 + mi][ni]);
            __builtin_amdgcn_s_setprio(0);
            BAR();
        }
        // ---- phase 2: kc=1, m-half 0 -------------------------------------
        {
            const int sg = ((4 + qd) ^ lx) * 8;
            for (int ni = 0; ni < 4; ++ni)
                bfr[ni] = *(const bf16x8*)&Bs[cur][(wn0 + ni * 16 + ln) * 64 + sg];
            for (int mi = 0; mi < 4; ++mi)
                af[mi] = *(const bf16x8*)&As[cur][(wm0 + mi * 16 + ln) * 64 + sg];
            if (pf) { SB(ks + 1, 2, nxt); SB(ks + 1, 3, nxt); }
            BAR();
            __builtin_amdgcn_s_setprio(1);
            for (int mi = 0; mi < 4; ++mi)
                for (int ni = 0; ni < 4; ++ni)
                    acc[mi][ni] = mfma16(af[mi], bfr[ni], acc[mi][ni]);
            __builtin_amdgcn_s_setprio(0);
            BAR();
        }
        // ---- phase 3: kc=1, m-half 1; boundary drain ---------------------
        {
            const int sg = ((4 + qd) ^ lx) * 8;
            for (int mi = 0; mi < 4; ++mi)
                af[mi] = *(const bf16x8*)&As[cur][(wm0 + 64 + mi * 16 + ln) * 64 + sg];
            BAR();
            __builtin_amdgcn_s_setprio(1);
            for (int mi = 0; mi < 4; ++mi)
                for (int ni = 0; ni < 4; ++ni)
                    acc[4 + mi][ni] = mfma16(af[mi], bfr[ni], acc[4 + mi][ni]);
            __builtin_amdgcn_s_setprio(0);
            WAITB(0);   // all own glo for tile ks+1 done; next phase-0 reads safe
        }
    }
#undef SA
#undef SB

    const float* bias = pa.bias[z];
    const float* bias2 = pa.bias2[z];
    bf16* out = pa.out[z];
    const int vst = pa.vst[z];
    for (int ni = 0; ni < 4; ++ni) {
        const int n = n0 + wn0 + ni * 16 + ln;
        const float bv = bias[n] + (bias2 ? bias2[n] : 0.0f);
        for (int mi = 0; mi < 8; ++mi) {
            const int mbase = m0 + wm0 + mi * 16 + qd * 4;
            f32x4 v = acc[mi][ni];
            if (vst) {
                const int b = mbase >> 10, s = mbase & 1023;
                bf16x4 pk;
                for (int r = 0; r < 4; ++r) pk[r] = (bf16)(v[r] + bv);
                *(bf16x4*)&out[((size_t)(b * 1024 + n)) * 1024 + s] = pk;
            } else {
                for (int r = 0; r < 4; ++r)
                    out[(size_t)(mbase + r) * 1024 + n] = (bf16)(v[r] + bv);
            }
        }
    }
}

// ---------------------------------------------------------------------------
// Attention: i-tile 128, j-tile 64, grid (16h,8it,4b)=512 = 2 blocks/CU
// (grid-capped, so the double buffer is occupancy-FREE: 66.5KB < 80KB).
// Per jt: BAR (all waves past reads of buf^1) -> stage jt+1 into buf^1
// (6 glo/wave) -> vmcnt(6)+BAR (buf jt resident; jt+1 in flight under
// compute) -> QK/softmax/PV on buf jt. vmcnt never drains to 0 until jt=15.
// K/QJ/V staged via glo+XOR-swizzle; V from fused Vsum GEMM ([d][s] bf16).
// mask from maskR registers (issued before BAR, covered by vmcnt(6)).
// ---------------------------------------------------------------------------
__global__ __launch_bounds__(256) void attn6_kernel(
    const bf16* __restrict__ Qb, const bf16* __restrict__ Kb, const bf16* __restrict__ TKb,
    const bf16* __restrict__ Vsum,
    const bf16* __restrict__ maskR, bf16* __restrict__ ctx)
{
    const int h = blockIdx.x, it = blockIdx.y, b = blockIdx.z;
    const int i0 = it * 128;
    __shared__ bf16 Ks[2][64 * 64];
    __shared__ bf16 QJs[2][64 * 64];
    __shared__ bf16 Vs[2][64 * 64];
    __shared__ bf16 Ps[128][68];
    const int t = threadIdx.x, lane = t & 63, w = t >> 6;
    const int ln = lane & 15, qd = lane >> 4;
    const int lx = ln & 7;
    const int rr = lane >> 3;
    const int cbs = ((lane & 7) ^ rr) * 8;
    const size_t baseQ = ((size_t)b * 1024) * 1024 + (size_t)h * 64;
    const size_t baseV = ((size_t)b * 1024 + h * 64) * 1024;

    bf16x8 qf[2][2], tkf[2][2];
    for (int si = 0; si < 2; ++si) {
        const size_t row = (size_t)(i0 + w * 32 + si * 16 + ln);
        for (int kc = 0; kc < 2; ++kc) {
            qf[si][kc]  = *(const bf16x8*)&Qb [baseQ + row * 1024 + kc * 32 + qd * 8];
            tkf[si][kc] = *(const bf16x8*)&TKb[baseQ + row * 1024 + kc * 32 + qd * 8];
        }
    }

    f32x4 O[2][4];
    f32x4 psum[2];
    for (int si = 0; si < 2; ++si) {
        psum[si] = (f32x4){0.f, 0.f, 0.f, 0.f};
        for (int dc = 0; dc < 4; ++dc) O[si][dc] = (f32x4){0.f, 0.f, 0.f, 0.f};
    }

    const float c1 = 0.045084439f;   // log2(e)/32
    const float c2 = 1.442695041f;   // log2(e)

    const size_t mtile0 = (((size_t)b * 8 + it) * 16) * 256 + t;

    // stage j-tile jt into buffer jt&1: 24 units (6 glo per wave)
    auto stage = [&](int jt) {
        const int buf = jt & 1;
        const int j0 = jt * 64;
        for (int i = 0; i < 6; ++i) {
            const int u = w * 6 + i;
            if (u < 8) {
                glo(&Kb[baseQ + (size_t)(j0 + u * 8 + rr) * 1024 + cbs], &Ks[buf][u * 512]);
            } else if (u < 16) {
                const int s = u - 8;
                glo(&Qb[baseQ + (size_t)(j0 + s * 8 + rr) * 1024 + cbs], &QJs[buf][s * 512]);
            } else {
                const int s = u - 16;
                glo(&Vsum[baseV + (size_t)(s * 8 + rr) * 1024 + j0 + cbs], &Vs[buf][s * 512]);
            }
        }
    };

    stage(0);

    for (int jt = 0; jt < 16; ++jt) {
        const int cur = jt & 1;
        bf16x8 mm[4];
        {
            const bf16* mb = &maskR[(mtile0 + (size_t)jt * 256) * 32];
            for (int c = 0; c < 4; ++c) mm[c] = *(const bf16x8*)&mb[c * 8];
        }
        BAR();                       // all waves done reading buf[cur^1]
        if (jt < 15) {
            stage(jt + 1);           // into buf[cur^1]; stays in flight
            WAITB(6);                // buf[cur] + mm resident; 6 outstanding
        } else {
            WAITB(0);
        }

        f32x4 sc[2][4];
        for (int jc = 0; jc < 4; ++jc) {
            bf16x8 kf[2], qjf[2];
            for (int kc = 0; kc < 2; ++kc) {
                const int sg = ((kc * 4 + qd) ^ lx) * 8;
                kf[kc]  = *(const bf16x8*)&Ks [cur][(jc * 16 + ln) * 64 + sg];
                qjf[kc] = *(const bf16x8*)&QJs[cur][(jc * 16 + ln) * 64 + sg];
            }
            for (int si = 0; si < 2; ++si) {
                f32x4 a = (f32x4){0.f, 0.f, 0.f, 0.f};
                a = mfma16(qf[si][0], kf[0], a);
                a = mfma16(qf[si][1], kf[1], a);
                a = mfma16(tkf[si][0], qjf[0], a);
                a = mfma16(tkf[si][1], qjf[1], a);
                sc[si][jc] = a;
            }
        }
        for (int si = 0; si < 2; ++si) {
            const int ibl = w * 32 + si * 16 + qd * 4;
            for (int jc = 0; jc < 4; ++jc) {
                const int jl = jc * 16 + ln;
                const int e = si * 4 + jc;
                for (int r = 0; r < 4; ++r) {
                    const float mval = (float)mm[e >> 1][(e & 1) * 4 + r];
                    const float p = exp2f(fmaf(sc[si][jc][r], c1, mval * c2));
                    psum[si][r] += p;
                    Ps[ibl + r][jl] = (bf16)p;
                }
            }
        }
        for (int kc = 0; kc < 2; ++kc) {
            bf16x8 pa[2], vb[4];
            for (int si = 0; si < 2; ++si) {
                bf16x4 lo = *(const bf16x4*)&Ps[w * 32 + si * 16 + ln][kc * 32 + qd * 8];
                bf16x4 hi = *(const bf16x4*)&Ps[w * 32 + si * 16 + ln][kc * 32 + qd * 8 + 4];
                for (int e = 0; e < 4; ++e) { pa[si][e] = lo[e]; pa[si][4 + e] = hi[e]; }
            }
            for (int dc = 0; dc < 4; ++dc) {
                const int vrow = dc * 16 + ln;
                const int sg = ((kc * 4 + qd) ^ lx) * 8;
                vb[dc] = *(const bf16x8*)&Vs[cur][vrow * 64 + sg];
            }
            for (int si = 0; si < 2; ++si)
                for (int dc = 0; dc < 4; ++dc)
                    O[si][dc] = mfma16(pa[si], vb[dc], O[si][dc]);
        }
    }

    for (int si = 0; si < 2; ++si) {
        for (int m = 1; m <= 8; m <<= 1) psum[si] += shflx4(psum[si], m);
        f32x4 rl;
        for (int r = 0; r < 4; ++r) rl[r] = 1.0f / psum[si][r];
        const int ibase = i0 + w * 32 + si * 16 + qd * 4;
        for (int dc = 0; dc < 4; ++dc) {
            const int d = h * 64 + dc * 16 + ln;
            f32x4 v = O[si][dc] * rl;
            for (int r = 0; r < 4; ++r)
                ctx[((size_t)b * 1024 + ibase + r) * 1024 + d] = (bf16)v[r];
        }
    }
}

// ---------------------------------------------------------------------------
// Final GEMM: out[m][n] = ctx[m][k]*WmT[n][k] + bm, fp32 out.
// 64m x 128n tile, grid (64 my, 8 nx) = 512 = 2 blocks/CU (grid-capped ->
// double buffer free: 48KB). Same counted-vmcnt pattern as attn6.
// ---------------------------------------------------------------------------
__global__ __launch_bounds__(256) void out_gemm(
    const bf16* __restrict__ A, const bf16* __restrict__ W,
    const float* __restrict__ bias, float* __restrict__ out)
{
    const int m0 = blockIdx.x * 64, n0 = blockIdx.y * 128;
    __shared__ bf16 As[2][64 * 64];
    __shared__ bf16 Bs[2][128 * 64];
    const int t = threadIdx.x, lane = t & 63, w = t >> 6;
    const int ln = lane & 15, qd = lane >> 4;
    const int wn0 = w * 32;
    const int rr = lane >> 3;
    const int cbs = ((lane & 7) ^ rr) * 8;
    const int lx = ln & 7;
    f32x4 acc[4][2];
    for (int i = 0; i < 4; ++i)
        for (int j = 0; j < 2; ++j)
            acc[i][j] = (f32x4){0.f, 0.f, 0.f, 0.f};

    auto stage = [&](int ks) {
        const int buf = ks & 1;
        const int bk = ks * 64;
        for (int i = 0; i < 6; ++i) {
            const int u = w * 6 + i;
            if (u < 8) {
                glo(&A[(size_t)(m0 + u * 8 + rr) * 1024 + bk + cbs], &As[buf][u * 512]);
            } else {
                const int sub = u - 8;
                glo(&W[(size_t)(n0 + sub * 8 + rr) * 1024 + bk + cbs], &Bs[buf][sub * 512]);
            }
        }
    };

    stage(0);

    for (int ks = 0; ks < 16; ++ks) {
        const int cur = ks & 1;
        BAR();                       // all waves done reading buf[cur^1]
        if (ks < 15) {
            stage(ks + 1);
            WAITB(6);
        } else {
            WAITB(0);
        }
        for (int kc = 0; kc < 2; ++kc) {
            const int sg = ((kc * 4 + qd) ^ lx) * 8;
            bf16x8 af[4], bfr[2];
            for (int mi = 0; mi < 4; ++mi)
                af[mi] = *(const bf16x8*)&As[cur][(mi * 16 + ln) * 64 + sg];
            for (int ni = 0; ni < 2; ++ni)
                bfr[ni] = *(const bf16x8*)&Bs[cur][(wn0 + ni * 16 + ln) * 64 + sg];
            for (int mi = 0; mi < 4; ++mi)
                for (int ni = 0; ni < 2; ++ni)
                    acc[mi][ni] = mfma16(af[mi], bfr[ni], acc[mi][ni]);
        }
    }
    for (int ni = 0; ni < 2; ++ni) {
        const int n = n0 + wn0 + ni * 16 + ln;
        const float bv = bias[n];
        for (int mi = 0; mi < 4; ++mi) {
            const int mbase = m0 + mi * 16 + qd * 4;
            f32x4 v = acc[mi][ni];
            for (int r = 0; r < 4; ++r)
                out[(size_t)(mbase + r) * 1024 + n] = v[r] + bv;
        }
    }
}

// ---------------------------------------------------------------------------
extern "C" void kernel_launch(void* const* d_in, const int* in_sizes, int n_in,
                              void* d_out, int out_size, void* d_ws, size_t ws_size,
                              hipStream_t stream)
{
    (void)in_sizes; (void)n_in; (void)out_size; (void)ws_size;
    const float* query  = (const float*)d_in[0];
    const float* key    = (const float*)d_in[1];
    const float* value  = (const float*)d_in[2];
    const float* time_k = (const float*)d_in[3];
    const float* time_v = (const float*)d_in[4];
    const float* mask   = (const float*)d_in[5];
    const float* Wq  = (const float*)d_in[6];  const float* bq  = (const float*)d_in[7];
    const float* Wk  = (const float*)d_in[8];  const float* bk  = (const float*)d_in[9];
    const float* Wv  = (const float*)d_in[10]; const float* bv  = (const float*)d_in[11];
    const float* Wtk = (const float*)d_in[12]; const float* btk = (const float*)d_in[13];
    const float* Wtv = (const float*)d_in[14]; const float* btv = (const float*)d_in[15];
    const float* Wm  = (const float*)d_in[16]; const float* bm  = (const float*)d_in[17];

    bf16* ws = (bf16*)d_ws;
    const size_t MM = (size_t)1024 * 1024;
    bf16* WTq  = ws + 0 * MM;        // [1024][1024]
    bf16* WTk  = ws + 1 * MM;
    bf16* WTtk = ws + 2 * MM;
    bf16* WTm  = ws + 3 * MM;
    bf16* WT5  = ws + 4 * MM;        // [1024][2048] = [Wv^T | Wtv^T]
    bf16* qbf  = ws + 6 * MM;        // [4096][1024] (dead after proj)
    bf16* kbf  = ws + 10 * MM;
    bf16* tkbf = ws + 14 * MM;
    bf16* A5   = ws + 18 * MM;       // [4096][2048] = [value | time_v] bf16
    bf16* Qb   = ws + 26 * MM;
    bf16* Kb   = ws + 30 * MM;
    bf16* TKb  = ws + 34 * MM;
    bf16* VsT  = ws + 38 * MM;       // Vsum [b*1024 + h*64 + d][s]
    bf16* ctx  = ws + 6 * MM;        // reuse qbf slab
    bf16* maskR = (bf16*)d_out;      // 8 MB scratch in d_out; dead before out_gemm

    PrepArgs pp;
    pp.w[0] = Wq;  pp.wdst[0] = WTq;        pp.wstride[0] = 1024;
    pp.w[1] = Wk;  pp.wdst[1] = WTk;        pp.wstride[1] = 1024;
    pp.w[2] = Wv;  pp.wdst[2] = WT5;        pp.wstride[2] = 2048;
    pp.w[3] = Wtk; pp.wdst[3] = WTtk;       pp.wstride[3] = 1024;
    pp.w[4] = Wtv; pp.wdst[4] = WT5 + 1024; pp.wstride[4] = 2048;
    pp.w[5] = Wm;  pp.wdst[5] = WTm;        pp.wstride[5] = 1024;
    pp.act[0] = query;  pp.adst[0] = qbf;       pp.astride[0] = 1024;
    pp.act[1] = key;    pp.adst[1] = kbf;       pp.astride[1] = 1024;
    pp.act[2] = value;  pp.adst[2] = A5;        pp.astride[2] = 2048;
    pp.act[3] = time_k; pp.adst[3] = tkbf;      pp.astride[3] = 1024;
    pp.act[4] = time_v; pp.adst[4] = A5 + 1024; pp.astride[4] = 2048;
    pp.mask = mask; pp.maskR = maskR;
    prep_kernel<<<dim3(16, 16, 15), 256, 0, stream>>>(pp);

    ProjArgs pa;
    // z0 = Vsum (2x work) first so long blocks start earliest.
    pa.A[0] = A5;   pa.W[0] = WT5;  pa.bias[0] = bv;  pa.bias2[0] = btv;
    pa.out[0] = VsT; pa.vst[0] = 1; pa.nk[0] = 32;
    pa.A[1] = qbf;  pa.W[1] = WTq;  pa.bias[1] = bq;  pa.bias2[1] = nullptr;
    pa.out[1] = Qb;  pa.vst[1] = 0; pa.nk[1] = 16;
    pa.A[2] = kbf;  pa.W[2] = WTk;  pa.bias[2] = bk;  pa.bias2[2] = nullptr;
    pa.out[2] = Kb;  pa.vst[2] = 0; pa.nk[2] = 16;
    pa.A[3] = tkbf; pa.W[3] = WTtk; pa.bias[3] = btk; pa.bias2[3] = nullptr;
    pa.out[3] = TKb; pa.vst[3] = 0; pa.nk[3] = 16;
    proj_gemm<<<dim3(16, 4, 4), 512, 0, stream>>>(pa);

    attn6_kernel<<<dim3(16, 8, 4), 256, 0, stream>>>(
        Qb, Kb, TKb, VsT, maskR, ctx);
    out_gemm<<<dim3(64, 8), 256, 0, stream>>>(ctx, WTm, bm, (float*)d_out);
}

// Round 9
// 311.514 us; speedup vs baseline: 1.0508x; 1.0508x over previous
//
#include <hip/hip_runtime.h>
#include <hip/hip_bf16.h>
#include <cstdint>
#include <cstddef>

typedef __bf16 bf16;
typedef bf16 bf16x8 __attribute__((ext_vector_type(8)));
typedef bf16 bf16x4 __attribute__((ext_vector_type(4)));
typedef float f32x4 __attribute__((ext_vector_type(4)));
typedef unsigned int u32;

#define DEV static __device__ __forceinline__

DEV f32x4 mfma16(bf16x8 a, bf16x8 b, f32x4 c) {
    return __builtin_amdgcn_mfma_f32_16x16x32_bf16(a, b, c, 0, 0, 0);
}

DEV f32x4 shflx4(f32x4 v, int m) {
    f32x4 r;
    for (int i = 0; i < 4; ++i) r[i] = __shfl_xor(v[i], m, 64);
    return r;
}

DEV bf16x8 cvt8(const float* p) {
    float4 f0 = *(const float4*)p;
    float4 f1 = *(const float4*)(p + 4);
    bf16x8 v;
    v[0] = (bf16)f0.x; v[1] = (bf16)f0.y; v[2] = (bf16)f0.z; v[3] = (bf16)f0.w;
    v[4] = (bf16)f1.x; v[5] = (bf16)f1.y; v[6] = (bf16)f1.z; v[7] = (bf16)f1.w;
    return v;
}

// async global->LDS, 16B/lane; global addr per-lane, LDS base wave-uniform.
DEV void glo(const bf16* g, bf16* l) {
    __builtin_amdgcn_global_load_lds(
        (const __attribute__((address_space(1))) u32*)g,
        (__attribute__((address_space(3))) u32*)l,
        16, 0, 0);
}

// fused "wait outstanding vmem <= n, then barrier" — counted, never reorder.
#define WAITB(n) asm volatile("s_waitcnt vmcnt(" #n ")\n\ts_barrier" ::: "memory")
#define BAR()    asm volatile("s_barrier" ::: "memory")

// ---------------------------------------------------------------------------
// Prep (merged): z<6 : weight transpose+cvt W[K][N]fp32 -> Wt[N][K]bf16
//                z 6..10 : fp32->bf16 cvt of the 5 activations
//                z 11..14 : maskprep for b = z-11 (blockIdx.y<8 active)
// grid (16, 16, 15), 256 threads.
// ---------------------------------------------------------------------------
struct PrepArgs {
    const float* w[6];
    const float* act[5];
    const float* mask;
    bf16* wdst[6];  int wstride[6];
    bf16* adst[5];  int astride[5];
    bf16* maskR;
};

__global__ __launch_bounds__(256) void prep_kernel(PrepArgs p)
{
    const int z = blockIdx.z;
    const int t = threadIdx.x;
    if (z < 6) {
        __shared__ bf16 tile[64][72];
        const float* src = p.w[z];
        bf16* out = p.wdst[z];
        const int os = p.wstride[z];
        const int r = t >> 3, c8 = (t & 7) * 8;
        const int row0 = blockIdx.y * 64, col0 = blockIdx.x * 64;
        *(bf16x8*)&tile[r][c8]      = cvt8(&src[(size_t)(row0 + r) * 1024 + col0 + c8]);
        *(bf16x8*)&tile[r + 32][c8] = cvt8(&src[(size_t)(row0 + r + 32) * 1024 + col0 + c8]);
        __syncthreads();
        for (int half = 0; half < 2; ++half) {
            int rr = r + half * 32;
            bf16x8 v;
            for (int j = 0; j < 8; ++j) v[j] = tile[c8 + j][rr];
            *(bf16x8*)&out[(size_t)(col0 + rr) * os + row0 + c8] = v;
        }
    } else if (z < 11) {
        const float* src = p.act[z - 6];
        bf16* dst = p.adst[z - 6];
        const int as = p.astride[z - 6];
        const size_t chunk = (size_t)(blockIdx.y * 16 + blockIdx.x) * 16384;
        for (int c = 0; c < 8; ++c) {
            const size_t off = chunk + (size_t)c * 2048 + (size_t)t * 8;
            const size_t row = off >> 10, col = off & 1023;
            *(bf16x8*)&dst[row * (size_t)as + col] = cvt8(&src[off]);
        }
    } else {
        // maskprep: mask[b][i][j] fp32 -> maskR[(b,it,jt)][tid][e] bf16
        if (blockIdx.y >= 8) return;
        const int jt = blockIdx.x, it = blockIdx.y, b = z - 11;
        __shared__ bf16 Mt[128 * 72];
        const int lane = t & 63, w = t >> 6;
        const int ln = lane & 15, qd = lane >> 4;
        {
            const int il = t >> 1, jh = (t & 1) * 32;
            const float* src = &p.mask[((size_t)b * 1024 + it * 128 + il) * 1024 + jt * 64 + jh];
            *(bf16x8*)&Mt[il * 72 + jh]      = cvt8(src);
            *(bf16x8*)&Mt[il * 72 + jh + 8]  = cvt8(src + 8);
            *(bf16x8*)&Mt[il * 72 + jh + 16] = cvt8(src + 16);
            *(bf16x8*)&Mt[il * 72 + jh + 24] = cvt8(src + 24);
        }
        __syncthreads();
        bf16 m[32];
        for (int si = 0; si < 2; ++si)
            for (int jc = 0; jc < 4; ++jc)
                for (int r = 0; r < 4; ++r) {
                    const int il = w * 32 + si * 16 + qd * 4 + r;
                    const int jl = jc * 16 + ln;
                    m[(si * 4 + jc) * 4 + r] = Mt[il * 72 + jl];
                }
        bf16* dst = &p.maskR[((((size_t)b * 8 + it) * 16 + jt) * 256 + t) * 32];
        for (int c = 0; c < 4; ++c)
            *(bf16x8*)&dst[c * 8] = *(const bf16x8*)&m[c * 8];
    }
}

// ---------------------------------------------------------------------------
// Projection GEMMs, 4 z-slices (r5-proven structure: 2-barrier per K-step,
// 128x128 tile, 4-5 blocks/CU; grid (32,8,4) = 1024 blocks = 1280 uniform
// work-units over 256 CUs = perfectly balanced. The 256² 4-phase schedule
// (r8) ran 1.5x faster per-block but its 320-unit granularity caps makespan
// at 2T = same 75us — granularity-locked; keep the balanced version.)
// z3 = fused Vsum GEMM: [value|time_v] @ [Wv;Wtv], K=2048, bias bv+btv.
// XOR swizzle (0 conflicts measured). linear%8 = my%8 -> same-A same XCD.
// ---------------------------------------------------------------------------
struct ProjArgs {
    const bf16* A[4];
    const bf16* W[4];
    const float* bias[4];
    const float* bias2[4];
    bf16* out[4];
    int vst[4];
    int nk[4];
};

__global__ __launch_bounds__(256) void proj_gemm(ProjArgs pa)
{
    const int z = blockIdx.z;
    const bf16* A = pa.A[z];
    const bf16* W = pa.W[z];
    const int nk = pa.nk[z];
    const int lda = nk << 6;
    const int m0 = blockIdx.x * 128, n0 = blockIdx.y * 128;
    __shared__ bf16 As[128 * 64];
    __shared__ bf16 Bs[128 * 64];
    const int t = threadIdx.x, lane = t & 63, w = t >> 6;
    const int ln = lane & 15, qd = lane >> 4;
    const int wm0 = (w >> 1) * 64, wn0 = (w & 1) * 64;
    const int sub0 = w * 4;
    const int rr = lane >> 3;
    const int cbs = (((lane & 7) ^ rr)) * 8;   // swizzled source column
    const int lx = ln & 7;                     // row&7 for fragment rows
    f32x4 acc[4][4];
    for (int i = 0; i < 4; ++i)
        for (int j = 0; j < 4; ++j)
            acc[i][j] = (f32x4){0.f, 0.f, 0.f, 0.f};
    for (int ks = 0; ks < nk; ++ks) {
        const int bk = ks * 64;
        __syncthreads();
        for (int i = 0; i < 4; ++i) {
            const int row = (sub0 + i) * 8 + rr;
            glo(&W[(size_t)(n0 + row) * lda + bk + cbs], &Bs[(sub0 + i) * 512]);
            glo(&A[(size_t)(m0 + row) * lda + bk + cbs], &As[(sub0 + i) * 512]);
        }
        __syncthreads();
        for (int kc = 0; kc < 2; ++kc) {
            const int sg = ((kc * 4 + qd) ^ lx) * 8;
            bf16x8 af[4], bfr[4];
            for (int mi = 0; mi < 4; ++mi)
                af[mi] = *(const bf16x8*)&As[(wm0 + mi * 16 + ln) * 64 + sg];
            for (int ni = 0; ni < 4; ++ni)
                bfr[ni] = *(const bf16x8*)&Bs[(wn0 + ni * 16 + ln) * 64 + sg];
            for (int mi = 0; mi < 4; ++mi)
                for (int ni = 0; ni < 4; ++ni)
                    acc[mi][ni] = mfma16(af[mi], bfr[ni], acc[mi][ni]);
        }
    }
    const float* bias = pa.bias[z];
    const float* bias2 = pa.bias2[z];
    bf16* out = pa.out[z];
    const int vst = pa.vst[z];
    for (int ni = 0; ni < 4; ++ni) {
        const int n = n0 + wn0 + ni * 16 + ln;
        const float bv = bias[n] + (bias2 ? bias2[n] : 0.0f);
        for (int mi = 0; mi < 4; ++mi) {
            const int mbase = m0 + wm0 + mi * 16 + qd * 4;
            f32x4 v = acc[mi][ni];
            if (vst) {
                const int b = mbase >> 10, s = mbase & 1023;
                bf16x4 pk;
                for (int r = 0; r < 4; ++r) pk[r] = (bf16)(v[r] + bv);
                *(bf16x4*)&out[((size_t)(b * 1024 + n)) * 1024 + s] = pk;
            } else {
                for (int r = 0; r < 4; ++r)
                    out[(size_t)(mbase + r) * 1024 + n] = (bf16)(v[r] + bv);
            }
        }
    }
}

// ---------------------------------------------------------------------------
// Attention — 8-WAVE re-parallelization (r9): 512 threads, each wave owns 16
// i-rows (was 4 waves x 32 rows). Same schedule, same dbuf, same barriers —
// pure TLP doubling: 2 blocks/CU -> 16 waves/CU (was 8), halving each wave's
// serial QK->softmax->PV chain. LDS unchanged 66.5KB (2 blocks/CU ok).
// Staging: 24 units = 3 glo/wave -> WAITB(3). maskR layout unchanged; new
// thread reads old tid = (w>>1)*64 + qd*16 + ln, si = w&1 folded into the
// base offset (local e = jc*4+r, 2x bf16x8 instead of 4).
// ---------------------------------------------------------------------------
__global__ __launch_bounds__(512) void attn6_kernel(
    const bf16* __restrict__ Qb, const bf16* __restrict__ Kb, const bf16* __restrict__ TKb,
    const bf16* __restrict__ Vsum,
    const bf16* __restrict__ maskR, bf16* __restrict__ ctx)
{
    const int h = blockIdx.x, it = blockIdx.y, b = blockIdx.z;
    const int i0 = it * 128;
    __shared__ bf16 Ks[2][64 * 64];
    __shared__ bf16 QJs[2][64 * 64];
    __shared__ bf16 Vs[2][64 * 64];
    __shared__ bf16 Ps[128][68];
    const int t = threadIdx.x, lane = t & 63, w = t >> 6;   // w 0..7
    const int ln = lane & 15, qd = lane >> 4;
    const int lx = ln & 7;
    const int rr = lane >> 3;
    const int cbs = ((lane & 7) ^ rr) * 8;
    const size_t baseQ = ((size_t)b * 1024) * 1024 + (size_t)h * 64;
    const size_t baseV = ((size_t)b * 1024 + h * 64) * 1024;

    // wave owns i-rows [i0 + w*16, i0 + w*16 + 16)
    bf16x8 qf[2], tkf[2];
    {
        const size_t row = (size_t)(i0 + w * 16 + ln);
        for (int kc = 0; kc < 2; ++kc) {
            qf[kc]  = *(const bf16x8*)&Qb [baseQ + row * 1024 + kc * 32 + qd * 8];
            tkf[kc] = *(const bf16x8*)&TKb[baseQ + row * 1024 + kc * 32 + qd * 8];
        }
    }

    f32x4 O[4];
    f32x4 psum = (f32x4){0.f, 0.f, 0.f, 0.f};
    for (int dc = 0; dc < 4; ++dc) O[dc] = (f32x4){0.f, 0.f, 0.f, 0.f};

    const float c1 = 0.045084439f;   // log2(e)/32
    const float c2 = 1.442695041f;   // log2(e)

    // old-layout tid for maskR: tid_old = (w>>1)*64 + qd*16 + ln; si = w&1.
    const size_t mtile0 = (((size_t)b * 8 + it) * 16) * 256
                        + (size_t)((w >> 1) * 64 + qd * 16 + ln);
    const int moff = (w & 1) * 16;   // si folded into element offset

    // stage j-tile jt into buffer jt&1: 24 units, 3 glo per wave
    auto stage = [&](int jt) {
        const int buf = jt & 1;
        const int j0 = jt * 64;
        for (int i = 0; i < 3; ++i) {
            const int u = w * 3 + i;
            if (u < 8) {
                glo(&Kb[baseQ + (size_t)(j0 + u * 8 + rr) * 1024 + cbs], &Ks[buf][u * 512]);
            } else if (u < 16) {
                const int s = u - 8;
                glo(&Qb[baseQ + (size_t)(j0 + s * 8 + rr) * 1024 + cbs], &QJs[buf][s * 512]);
            } else {
                const int s = u - 16;
                glo(&Vsum[baseV + (size_t)(s * 8 + rr) * 1024 + j0 + cbs], &Vs[buf][s * 512]);
            }
        }
    };

    stage(0);

    for (int jt = 0; jt < 16; ++jt) {
        const int cur = jt & 1;
        bf16x8 mm[2];
        {
            const bf16* mb = &maskR[(mtile0 + (size_t)jt * 256) * 32 + moff];
            mm[0] = *(const bf16x8*)&mb[0];
            mm[1] = *(const bf16x8*)&mb[8];
        }
        BAR();                       // all waves done reading buf[cur^1]
        if (jt < 15) {
            stage(jt + 1);           // into buf[cur^1]; stays in flight
            WAITB(3);                // buf[cur] resident; 3 outstanding
        } else {
            WAITB(0);
        }

        f32x4 sc[4];
        for (int jc = 0; jc < 4; ++jc) {
            bf16x8 kf[2], qjf[2];
            for (int kc = 0; kc < 2; ++kc) {
                const int sg = ((kc * 4 + qd) ^ lx) * 8;
                kf[kc]  = *(const bf16x8*)&Ks [cur][(jc * 16 + ln) * 64 + sg];
                qjf[kc] = *(const bf16x8*)&QJs[cur][(jc * 16 + ln) * 64 + sg];
            }
            f32x4 a = (f32x4){0.f, 0.f, 0.f, 0.f};
            a = mfma16(qf[0], kf[0], a);
            a = mfma16(qf[1], kf[1], a);
            a = mfma16(tkf[0], qjf[0], a);
            a = mfma16(tkf[1], qjf[1], a);
            sc[jc] = a;
        }
        {
            const int ibl = w * 16 + qd * 4;
            for (int jc = 0; jc < 4; ++jc) {
                const int jl = jc * 16 + ln;
                for (int r = 0; r < 4; ++r) {
                    const float mval = (float)mm[jc >> 1][(jc & 1) * 4 + r];
                    const float p = exp2f(fmaf(sc[jc][r], c1, mval * c2));
                    psum[r] += p;
                    Ps[ibl + r][jl] = (bf16)p;
                }
            }
        }
        for (int kc = 0; kc < 2; ++kc) {
            bf16x8 pa, vb[4];
            {
                bf16x4 lo = *(const bf16x4*)&Ps[w * 16 + ln][kc * 32 + qd * 8];
                bf16x4 hi = *(const bf16x4*)&Ps[w * 16 + ln][kc * 32 + qd * 8 + 4];
                for (int e = 0; e < 4; ++e) { pa[e] = lo[e]; pa[4 + e] = hi[e]; }
            }
            for (int dc = 0; dc < 4; ++dc) {
                const int vrow = dc * 16 + ln;
                const int sg = ((kc * 4 + qd) ^ lx) * 8;
                vb[dc] = *(const bf16x8*)&Vs[cur][vrow * 64 + sg];
            }
            for (int dc = 0; dc < 4; ++dc)
                O[dc] = mfma16(pa, vb[dc], O[dc]);
        }
    }

    for (int m = 1; m <= 8; m <<= 1) psum += shflx4(psum, m);
    f32x4 rl;
    for (int r = 0; r < 4; ++r) rl[r] = 1.0f / psum[r];
    const int ibase = i0 + w * 16 + qd * 4;
    for (int dc = 0; dc < 4; ++dc) {
        const int d = h * 64 + dc * 16 + ln;
        f32x4 v = O[dc] * rl;
        for (int r = 0; r < 4; ++r)
            ctx[((size_t)b * 1024 + ibase + r) * 1024 + d] = (bf16)v[r];
    }
}

// ---------------------------------------------------------------------------
// Final GEMM: out[m][n] = ctx[m][k]*WmT[n][k] + bm, fp32 out.
// 64m x 128n tile, grid (64 my, 8 nx) = 512 = 2 blocks/CU (grid-capped ->
// double buffer free: 48KB). Same counted-vmcnt pattern as attn6.
// ---------------------------------------------------------------------------
__global__ __launch_bounds__(256) void out_gemm(
    const bf16* __restrict__ A, const bf16* __restrict__ W,
    const float* __restrict__ bias, float* __restrict__ out)
{
    const int m0 = blockIdx.x * 64, n0 = blockIdx.y * 128;
    __shared__ bf16 As[2][64 * 64];
    __shared__ bf16 Bs[2][128 * 64];
    const int t = threadIdx.x, lane = t & 63, w = t >> 6;
    const int ln = lane & 15, qd = lane >> 4;
    const int wn0 = w * 32;
    const int rr = lane >> 3;
    const int cbs = ((lane & 7) ^ rr) * 8;
    const int lx = ln & 7;
    f32x4 acc[4][2];
    for (int i = 0; i < 4; ++i)
        for (int j = 0; j < 2; ++j)
            acc[i][j] = (f32x4){0.f, 0.f, 0.f, 0.f};

    auto stage = [&](int ks) {
        const int buf = ks & 1;
        const int bk = ks * 64;
        for (int i = 0; i < 6; ++i) {
            const int u = w * 6 + i;
            if (u < 8) {
                glo(&A[(size_t)(m0 + u * 8 + rr) * 1024 + bk + cbs], &As[buf][u * 512]);
            } else {
                const int sub = u - 8;
                glo(&W[(size_t)(n0 + sub * 8 + rr) * 1024 + bk + cbs], &Bs[buf][sub * 512]);
            }
        }
    };

    stage(0);

    for (int ks = 0; ks < 16; ++ks) {
        const int cur = ks & 1;
        BAR();                       // all waves done reading buf[cur^1]
        if (ks < 15) {
            stage(ks + 1);
            WAITB(6);
        } else {
            WAITB(0);
        }
        for (int kc = 0; kc < 2; ++kc) {
            const int sg = ((kc * 4 + qd) ^ lx) * 8;
            bf16x8 af[4], bfr[2];
            for (int mi = 0; mi < 4; ++mi)
                af[mi] = *(const bf16x8*)&As[cur][(mi * 16 + ln) * 64 + sg];
            for (int ni = 0; ni < 2; ++ni)
                bfr[ni] = *(const bf16x8*)&Bs[cur][(wn0 + ni * 16 + ln) * 64 + sg];
            for (int mi = 0; mi < 4; ++mi)
                for (int ni = 0; ni < 2; ++ni)
                    acc[mi][ni] = mfma16(af[mi], bfr[ni], acc[mi][ni]);
        }
    }
    for (int ni = 0; ni < 2; ++ni) {
        const int n = n0 + wn0 + ni * 16 + ln;
        const float bv = bias[n];
        for (int mi = 0; mi < 4; ++mi) {
            const int mbase = m0 + mi * 16 + qd * 4;
            f32x4 v = acc[mi][ni];
            for (int r = 0; r < 4; ++r)
                out[(size_t)(mbase + r) * 1024 + n] = v[r] + bv;
        }
    }
}

// ---------------------------------------------------------------------------
extern "C" void kernel_launch(void* const* d_in, const int* in_sizes, int n_in,
                              void* d_out, int out_size, void* d_ws, size_t ws_size,
                              hipStream_t stream)
{
    (void)in_sizes; (void)n_in; (void)out_size; (void)ws_size;
    const float* query  = (const float*)d_in[0];
    const float* key    = (const float*)d_in[1];
    const float* value  = (const float*)d_in[2];
    const float* time_k = (const float*)d_in[3];
    const float* time_v = (const float*)d_in[4];
    const float* mask   = (const float*)d_in[5];
    const float* Wq  = (const float*)d_in[6];  const float* bq  = (const float*)d_in[7];
    const float* Wk  = (const float*)d_in[8];  const float* bk  = (const float*)d_in[9];
    const float* Wv  = (const float*)d_in[10]; const float* bv  = (const float*)d_in[11];
    const float* Wtk = (const float*)d_in[12]; const float* btk = (const float*)d_in[13];
    const float* Wtv = (const float*)d_in[14]; const float* btv = (const float*)d_in[15];
    const float* Wm  = (const float*)d_in[16]; const float* bm  = (const float*)d_in[17];

    bf16* ws = (bf16*)d_ws;
    const size_t MM = (size_t)1024 * 1024;
    bf16* WTq  = ws + 0 * MM;        // [1024][1024]
    bf16* WTk  = ws + 1 * MM;
    bf16* WTtk = ws + 2 * MM;
    bf16* WTm  = ws + 3 * MM;
    bf16* WT5  = ws + 4 * MM;        // [1024][2048] = [Wv^T | Wtv^T]
    bf16* qbf  = ws + 6 * MM;        // [4096][1024] (dead after proj)
    bf16* kbf  = ws + 10 * MM;
    bf16* tkbf = ws + 14 * MM;
    bf16* A5   = ws + 18 * MM;       // [4096][2048] = [value | time_v] bf16
    bf16* Qb   = ws + 26 * MM;
    bf16* Kb   = ws + 30 * MM;
    bf16* TKb  = ws + 34 * MM;
    bf16* VsT  = ws + 38 * MM;       // Vsum [b*1024 + h*64 + d][s]
    bf16* ctx  = ws + 6 * MM;        // reuse qbf slab
    bf16* maskR = (bf16*)d_out;      // 8 MB scratch in d_out; dead before out_gemm

    PrepArgs pp;
    pp.w[0] = Wq;  pp.wdst[0] = WTq;        pp.wstride[0] = 1024;
    pp.w[1] = Wk;  pp.wdst[1] = WTk;        pp.wstride[1] = 1024;
    pp.w[2] = Wv;  pp.wdst[2] = WT5;        pp.wstride[2] = 2048;
    pp.w[3] = Wtk; pp.wdst[3] = WTtk;       pp.wstride[3] = 1024;
    pp.w[4] = Wtv; pp.wdst[4] = WT5 + 1024; pp.wstride[4] = 2048;
    pp.w[5] = Wm;  pp.wdst[5] = WTm;        pp.wstride[5] = 1024;
    pp.act[0] = query;  pp.adst[0] = qbf;       pp.astride[0] = 1024;
    pp.act[1] = key;    pp.adst[1] = kbf;       pp.astride[1] = 1024;
    pp.act[2] = value;  pp.adst[2] = A5;        pp.astride[2] = 2048;
    pp.act[3] = time_k; pp.adst[3] = tkbf;      pp.astride[3] = 1024;
    pp.act[4] = time_v; pp.adst[4] = A5 + 1024; pp.astride[4] = 2048;
    pp.mask = mask; pp.maskR = maskR;
    prep_kernel<<<dim3(16, 16, 15), 256, 0, stream>>>(pp);

    ProjArgs pa;
    pa.A[0] = qbf;  pa.W[0] = WTq;  pa.bias[0] = bq;  pa.bias2[0] = nullptr;
    pa.out[0] = Qb;  pa.vst[0] = 0; pa.nk[0] = 16;
    pa.A[1] = kbf;  pa.W[1] = WTk;  pa.bias[1] = bk;  pa.bias2[1] = nullptr;
    pa.out[1] = Kb;  pa.vst[1] = 0; pa.nk[1] = 16;
    pa.A[2] = tkbf; pa.W[2] = WTtk; pa.bias[2] = btk; pa.bias2[2] = nullptr;
    pa.out[2] = TKb; pa.vst[2] = 0; pa.nk[2] = 16;
    pa.A[3] = A5;   pa.W[3] = WT5;  pa.bias[3] = bv;  pa.bias2[3] = btv;
    pa.out[3] = VsT; pa.vst[3] = 1; pa.nk[3] = 32;
    proj_gemm<<<dim3(32, 8, 4), 256, 0, stream>>>(pa);

    attn6_kernel<<<dim3(16, 8, 4), 512, 0, stream>>>(
        Qb, Kb, TKb, VsT, maskR, ctx);
    out_gemm<<<dim3(64, 8), 256, 0, stream>>>(ctx, WTm, bm, (float*)d_out);
}